// Round 8
// baseline (41.744 us; speedup 1.0000x reference)
//
#include <hip/hip_runtime.h>
#include <math.h>

#define NB 2
#define NN 1024
#define NH 64
#define NK 8
#define ITILE 8

typedef float f32x2 __attribute__((ext_vector_type(2)));
typedef float f32x16 __attribute__((ext_vector_type(16)));
typedef _Float16 half8 __attribute__((ext_vector_type(8)));
typedef _Float16 half2t __attribute__((ext_vector_type(2)));
typedef __fp16 fp16x2 __attribute__((ext_vector_type(2)));
typedef unsigned u32x2 __attribute__((ext_vector_type(2)));

union FragU { uint32_t u[4]; uint4 q; half8 h; };
union H2U  { half2t h; fp16x2 p; uint32_t u; };
union C32U { f32x16 v; f32x2 d[8]; float f[16]; };

static __device__ __forceinline__ uint32_t pk_rne(float a, float b) {
    half2t t; t[0] = (_Float16)a; t[1] = (_Float16)b;
    H2U r; r.h = t; return r.u;
}

// lane-half exchange: w0 = [a_lo | b_lo], w2 = [a_hi | b_hi]
static __device__ __forceinline__ void half_swap(uint32_t a, uint32_t b,
                                                 uint32_t& w0, uint32_t& w2) {
#if __has_builtin(__builtin_amdgcn_permlane32_swap)
    u32x2 s = __builtin_amdgcn_permlane32_swap(a, b, false, false);
    w0 = s[0]; w2 = s[1];
#else
    const int hi = (threadIdx.x & 63) >> 5;
    uint32_t pa = __shfl_xor(a, 32), pb = __shfl_xor(b, 32);
    w0 = hi ? pb : a;
    w2 = hi ? b : pa;
#endif
}

// cross-half sum without DS: own + partner(lane^32), pure VALU
static __device__ __forceinline__ float wave_sum_half(float v) {
#if __has_builtin(__builtin_amdgcn_permlane32_swap)
    union { float f; uint32_t u; } a, r0, r1;
    a.f = v;
    u32x2 s = __builtin_amdgcn_permlane32_swap(a.u, a.u, false, false);
    r0.u = s[0]; r1.u = s[1];
    return r0.f + r1.f;
#else
    return v + __shfl_xor(v, 32);
#endif
}

// ---------------- prep ----------------
// blocks 0..7   : pt[b][n] = (x, y, cos h, sin h) f32
// blocks 8..519 : qpack A1-frags (32x32x16), 64 lane-slots per (b,i,tile):
//                 slot h&31 = 16B {(qc,qs),(qx,qy),(w0,cn),0}; slots 32..63 = 0
// block 520     : w2pack A2-frags (32x32x16), 4 K-chunks:
//                 chunk c, lane l: row k_out=l&31 (<8 real), k e=0..7 -> h=16c+8*(l>>5)+e
__global__ void prep_kernel(const float* __restrict__ rv,
                            const float* __restrict__ W1,
                            const float* __restrict__ b1,
                            const float* __restrict__ W2,
                            float* __restrict__ pt,
                            uint4* __restrict__ qpack,
                            uint4* __restrict__ w2pack) {
    const int tid = threadIdx.x;
    const int bid = blockIdx.x;
    if (bid < 8) {
        const int idx = bid * 256 + tid;  // 0..2047
        const float x0 = rv[idx*4+0], y0 = rv[idx*4+1];
        const float vx = rv[idx*4+2] - x0, vy = rv[idx*4+3] - y0;
        const float rinv = rsqrtf(fmaf(vx, vx, vy * vy));
        float4 o; o.x = x0; o.y = y0; o.z = vx * rinv; o.w = vy * rinv;
        reinterpret_cast<float4*>(pt)[idx] = o;
    } else if (bid < 520) {
        __shared__ float mean[6];
        if (tid < 5)       { float m = 0.f; for (int h = 0; h < NH; ++h) m += W1[tid*NH+h]; mean[tid] = m * (1.f/NH); }
        else if (tid == 5) { float m = 0.f; for (int h = 0; h < NH; ++h) m += b1[h];        mean[5]   = m * (1.f/NH); }
        __syncthreads();
        const int gid = (bid - 8) * 256 + tid;     // (b,i,h)
        const int b = gid >> 16, i = (gid >> 6) & 1023, h = gid & 63;
        const float x0 = rv[(b*NN+i)*4+0], y0 = rv[(b*NN+i)*4+1];
        const float vx = rv[(b*NN+i)*4+2] - x0, vy = rv[(b*NN+i)*4+3] - y0;
        const float rinv = rsqrtf(fmaf(vx, vx, vy * vy));
        const float ci = vx * rinv, si = vy * rinv;
        const float w0 = W1[0*NH+h]-mean[0], w1 = W1[1*NH+h]-mean[1], w2 = W1[2*NH+h]-mean[2],
                    w3 = W1[3*NH+h]-mean[3], w4 = W1[4*NH+h]-mean[4];
        const float bb = b1[h] - mean[5];
        const float qc = fmaf(w1, ci,  w2 * si);
        const float qs = fmaf(w1, si, -w2 * ci);
        const float qx = fmaf(-w3, ci,  w4 * si);
        const float qy = fmaf(-w3, si, -w4 * ci);
        const float cn = fmaf(w3, fmaf(x0, ci, y0 * si), fmaf(w4, fmaf(y0, ci, -x0 * si), bb));
        uint4 v;
        v.x = pk_rne(qc, qs); v.y = pk_rne(qx, qy); v.z = pk_rne(w0, cn); v.w = 0u;
        const size_t qb = ((size_t)(b*NN + i)*2 + (h >> 5))*64 + (h & 31);
        qpack[qb] = v;
        qpack[qb + 32] = make_uint4(0,0,0,0);
    } else {
        // w2pack: 4 chunks x 64 lanes
        const int c = tid >> 6, l = tid & 63;
        const int row = l & 31;
        const int hb = 16*c + 8*(l >> 5);
        uint32_t dw[4];
        for (int t = 0; t < 4; ++t) {
            const int h0 = hb + 2*t;
            const float a = (row < 8) ? W2[h0*NK + row]     : 0.f;
            const float d = (row < 8) ? W2[(h0+1)*NK + row] : 0.f;
            dw[t] = pk_rne(a, d);
        }
        uint4 v; v.x = dw[0]; v.y = dw[1]; v.z = dw[2]; v.w = dw[3];
        w2pack[c*64 + l] = v;
    }
}

// sumsq of one 32x32 C pair (mu==0 exact by pre-centering)
#define SUMSQ(cA, cB, sqv) { \
    f32x2 q0 = cA.d[0]*cA.d[0], q1 = cA.d[1]*cA.d[1], q2 = cA.d[2]*cA.d[2], q3 = cA.d[3]*cA.d[3]; \
    q0 = __builtin_elementwise_fma(cA.d[4], cA.d[4], q0); \
    q1 = __builtin_elementwise_fma(cA.d[5], cA.d[5], q1); \
    q2 = __builtin_elementwise_fma(cA.d[6], cA.d[6], q2); \
    q3 = __builtin_elementwise_fma(cA.d[7], cA.d[7], q3); \
    q0 = __builtin_elementwise_fma(cB.d[0], cB.d[0], q0); \
    q1 = __builtin_elementwise_fma(cB.d[1], cB.d[1], q1); \
    q2 = __builtin_elementwise_fma(cB.d[2], cB.d[2], q2); \
    q3 = __builtin_elementwise_fma(cB.d[3], cB.d[3], q3); \
    q0 = __builtin_elementwise_fma(cB.d[4], cB.d[4], q0); \
    q1 = __builtin_elementwise_fma(cB.d[5], cB.d[5], q1); \
    q2 = __builtin_elementwise_fma(cB.d[6], cB.d[6], q2); \
    q3 = __builtin_elementwise_fma(cB.d[7], cB.d[7], q3); \
    q0 += q1; q2 += q3; q0 += q2; \
    sqv = q0[0] + q0[1]; }

// ---------------- main ----------------
// Per wave: 32 j, ITILE i in ILP-2 pairs (two independent chains in flight).
// GEMM1: 2x mfma_32x32x16 per i. LN: mu==0 exact; inv=rsqrt(E[x^2]+eps);
// cross-half reduce via permlane32_swap (no DS). Normalize+relu packed f16.
// Y C->B layout via permlane32_swap; GEMM2: 4 chained mfma_32x32x16 with
// b2 folded into acc init. 4 full-wave coalesced stores per i.
__global__ __launch_bounds__(256, 2) void rpe_kernel(
    const float* __restrict__ pt,
    const uint4* __restrict__ qpack,
    const uint4* __restrict__ w2pack,
    const float* __restrict__ gamma,
    const float* __restrict__ beta,
    const float* __restrict__ b2,
    float* __restrict__ out) {
    const int tid  = threadIdx.x;
    const int wave = tid >> 6;
    const int lane = tid & 63;
    const int jj   = lane & 31;
    const int hi   = lane >> 5;
    const int b  = blockIdx.z;
    const int j0 = blockIdx.x * 128 + wave * 32;
    const int iBase = blockIdx.y * ITILE;

    const uint32_t hm = hi ? 0u : 0xFFFFFFFFu;

    const float4 pj = reinterpret_cast<const float4*>(pt)[b*NN + j0 + jj];
    const float xj = pj.x, yj = pj.y;
    const uint32_t d0 = pk_rne(pj.z, pj.w) & hm;
    const uint32_t d1 = pk_rne(xj, yj) & hm;

    // gamma/beta fp16 pairs: word (T,m) -> rows h0,h0+1 ; h0 = 32T+8(m>>1)+2(m&1)+4hi
    uint32_t gph[16], bph[16];
#pragma unroll
    for (int T = 0; T < 2; ++T)
#pragma unroll
        for (int m = 0; m < 8; ++m) {
            const int h0 = 32*T + 8*(m>>1) + 2*(m&1) + 4*hi;
            gph[T*8+m] = pk_rne(gamma[h0], gamma[h0+1]);
            bph[T*8+m] = pk_rne(beta[h0],  beta[h0+1]);
        }

    FragU a2[4];
#pragma unroll
    for (int c = 0; c < 4; ++c) a2[c].q = w2pack[c*64 + lane];
    float b2v[4];
#pragma unroll
    for (int r = 0; r < 4; ++r) b2v[r] = b2[4*hi + r];

    const uint4* qrow = qpack + (size_t)(b*NN + iBase) * 128;
    const float4* ptb = reinterpret_cast<const float4*>(pt) + b*NN + iBase;

    uint4 nqA0 = qrow[lane],        nqB0 = qrow[64 + lane];
    uint4 nqA1 = qrow[128 + lane],  nqB1 = qrow[192 + lane];
    float4 piv0 = ptb[0], piv1 = ptb[1];

    const f32x16 z16 = {0,0,0,0,0,0,0,0,0,0,0,0,0,0,0,0};
    half2t z2; z2[0] = (_Float16)0.f; z2[1] = (_Float16)0.f;
    const size_t plane = (size_t)NN * NN;
    float* op = out + (size_t)(b*NK + 4*hi)*plane + (size_t)iBase*NN + (j0 + jj);

#define NORM_GEMM2_STORE(cA, cB, inv, o_) { \
        H2U inv2u; inv2u.p = __builtin_amdgcn_cvt_pkrtz(inv, inv); \
        const half2t inv2 = inv2u.h; \
        uint32_t yw[16]; \
        _Pragma("unroll") \
        for (int m = 0; m < 8; ++m) { \
            H2U x; x.p = __builtin_amdgcn_cvt_pkrtz(cA.d[m][0], cA.d[m][1]); \
            half2t xh = x.h * inv2; \
            H2U gg, bb; gg.u = gph[m]; bb.u = bph[m]; \
            half2t y = __builtin_elementwise_fma(xh, gg.h, bb.h); \
            y = __builtin_elementwise_max(y, z2); \
            H2U o; o.h = y; yw[m] = o.u; \
        } \
        _Pragma("unroll") \
        for (int m = 0; m < 8; ++m) { \
            H2U x; x.p = __builtin_amdgcn_cvt_pkrtz(cB.d[m][0], cB.d[m][1]); \
            half2t xh = x.h * inv2; \
            H2U gg, bb; gg.u = gph[8+m]; bb.u = bph[8+m]; \
            half2t y = __builtin_elementwise_fma(xh, gg.h, bb.h); \
            y = __builtin_elementwise_max(y, z2); \
            H2U o; o.h = y; yw[8+m] = o.u; \
        } \
        C32U c2; c2.v = z16; \
        c2.f[0] = b2v[0]; c2.f[1] = b2v[1]; c2.f[2] = b2v[2]; c2.f[3] = b2v[3]; \
        _Pragma("unroll") \
        for (int c = 0; c < 4; ++c) { \
            uint32_t w0, w1, w2, w3; \
            half_swap(yw[4*c + 0], yw[4*c + 2], w0, w2); \
            half_swap(yw[4*c + 1], yw[4*c + 3], w1, w3); \
            FragU Bf; Bf.u[0] = w0; Bf.u[1] = w1; Bf.u[2] = w2; Bf.u[3] = w3; \
            c2.v = __builtin_amdgcn_mfma_f32_32x32x16_f16(a2[c].h, Bf.h, c2.v, 0, 0, 0); \
        } \
        o_[0]       = c2.f[0]; \
        o_[plane]   = c2.f[1]; \
        o_[2*plane] = c2.f[2]; \
        o_[3*plane] = c2.f[3]; }

    for (int ii = 0; ii < ITILE; ii += 2) {
        FragU qf00, qf01, qf10, qf11;
        qf00.q = nqA0; qf01.q = nqB0; qf10.q = nqA1; qf11.q = nqB1;
        const float pix0 = piv0.x, piy0 = piv0.y;
        const float pix1 = piv1.x, piy1 = piv1.y;
        const int nx = (ii + 2 < ITILE) ? (ii + 2) : ii;
        nqA0 = qrow[nx*128 + lane];       nqB0 = qrow[nx*128 + 64 + lane];
        nqA1 = qrow[nx*128 + 128 + lane]; nqB1 = qrow[nx*128 + 192 + lane];
        piv0 = ptb[nx]; piv1 = ptb[nx + 1];

        // features (two independent chains)
        const float dx0 = pix0 - xj, dy0 = piy0 - yj;
        const float dx1 = pix1 - xj, dy1 = piy1 - yj;
        const float g0v0 = logf(sqrtf(fmaf(dx0, dx0, dy0 * dy0)) + 1e-5f);
        const float g0v1 = logf(sqrtf(fmaf(dx1, dx1, dy1 * dy1)) + 1e-5f);
        H2U e0; e0.p = __builtin_amdgcn_cvt_pkrtz(g0v0, 1.0f);
        H2U e1; e1.p = __builtin_amdgcn_cvt_pkrtz(g0v1, 1.0f);
        FragU bf0; bf0.u[0] = d0; bf0.u[1] = d1; bf0.u[2] = e0.u & hm; bf0.u[3] = 0u;
        FragU bf1; bf1.u[0] = d0; bf1.u[1] = d1; bf1.u[2] = e1.u & hm; bf1.u[3] = 0u;

        C32U cA0, cB0, cA1, cB1;
        cA0.v = __builtin_amdgcn_mfma_f32_32x32x16_f16(qf00.h, bf0.h, z16, 0, 0, 0);
        cB0.v = __builtin_amdgcn_mfma_f32_32x32x16_f16(qf01.h, bf0.h, z16, 0, 0, 0);
        cA1.v = __builtin_amdgcn_mfma_f32_32x32x16_f16(qf10.h, bf1.h, z16, 0, 0, 0);
        cB1.v = __builtin_amdgcn_mfma_f32_32x32x16_f16(qf11.h, bf1.h, z16, 0, 0, 0);

        float sq0, sq1;
        SUMSQ(cA0, cB0, sq0)
        SUMSQ(cA1, cB1, sq1)
        sq0 = wave_sum_half(sq0);
        sq1 = wave_sum_half(sq1);
        const float inv0 = rsqrtf(fmaf(sq0, 1.f/64.f, 1e-5f));
        const float inv1 = rsqrtf(fmaf(sq1, 1.f/64.f, 1e-5f));

        float* o0 = op + (size_t)ii * NN;
        float* o1 = o0 + NN;
        NORM_GEMM2_STORE(cA0, cB0, inv0, o0)
        NORM_GEMM2_STORE(cA1, cB1, inv1, o1)
    }
}

extern "C" void kernel_launch(void* const* d_in, const int* in_sizes, int n_in,
                              void* d_out, int out_size, void* d_ws, size_t ws_size,
                              hipStream_t stream) {
    const float* rv    = (const float*)d_in[0];
    const float* W1    = (const float*)d_in[1];
    const float* b1    = (const float*)d_in[2];
    const float* gamma = (const float*)d_in[3];
    const float* beta  = (const float*)d_in[4];
    const float* W2    = (const float*)d_in[5];
    const float* b2    = (const float*)d_in[6];
    float* out = (float*)d_out;

    float* ws = (float*)d_ws;
    float* pt      = ws;                                    // 32 KB
    uint4* qpack   = (uint4*)(ws + 8192);                   // 2048*2*64*16B = 4 MB
    uint4* w2pack  = (uint4*)(ws + 8192 + 1048576 + 16384); // 4 KB

    prep_kernel<<<521, 256, 0, stream>>>(rv, W1, b1, W2, pt, qpack, w2pack);

    dim3 grid(NN / 128, NN / ITILE, NB);
    rpe_kernel<<<grid, 256, 0, stream>>>(pt, qpack, w2pack, gamma, beta, b2, out);
}

// Round 9
// 40.229 us; speedup vs baseline: 1.0377x; 1.0377x over previous
//
#include <hip/hip_runtime.h>
#include <math.h>

#define NB 2
#define NN 1024
#define NH 64
#define NK 8
#define ITILE 8

typedef float f32x2 __attribute__((ext_vector_type(2)));
typedef float f32x16 __attribute__((ext_vector_type(16)));
typedef _Float16 half8 __attribute__((ext_vector_type(8)));
typedef _Float16 half2t __attribute__((ext_vector_type(2)));
typedef __fp16 fp16x2 __attribute__((ext_vector_type(2)));
typedef unsigned u32x2 __attribute__((ext_vector_type(2)));

union FragU { uint32_t u[4]; uint4 q; half8 h; };
union H2U  { half2t h; fp16x2 p; uint32_t u; };
union C32U { f32x16 v; f32x2 d[8]; float f[16]; };

static __device__ __forceinline__ uint32_t pk_rne(float a, float b) {
    half2t t; t[0] = (_Float16)a; t[1] = (_Float16)b;
    H2U r; r.h = t; return r.u;
}

// lane-half exchange: w0 = [a_lo | b_lo], w2 = [a_hi | b_hi]
static __device__ __forceinline__ void half_swap(uint32_t a, uint32_t b,
                                                 uint32_t& w0, uint32_t& w2) {
#if __has_builtin(__builtin_amdgcn_permlane32_swap)
    u32x2 s = __builtin_amdgcn_permlane32_swap(a, b, false, false);
    w0 = s[0]; w2 = s[1];
#else
    const int hi = (threadIdx.x & 63) >> 5;
    uint32_t pa = __shfl_xor(a, 32), pb = __shfl_xor(b, 32);
    w0 = hi ? pb : a;
    w2 = hi ? b : pa;
#endif
}

// cross-half sum without DS: own + partner(lane^32), pure VALU
static __device__ __forceinline__ float wave_sum_half(float v) {
#if __has_builtin(__builtin_amdgcn_permlane32_swap)
    union { float f; uint32_t u; } a, r0, r1;
    a.f = v;
    u32x2 s = __builtin_amdgcn_permlane32_swap(a.u, a.u, false, false);
    r0.u = s[0]; r1.u = s[1];
    return r0.f + r1.f;
#else
    return v + __shfl_xor(v, 32);
#endif
}

// ---------------- prep ----------------
// blocks 0..7 : pt[b][n] = (x, y, cos h, sin h) f32
// block 8     : (a) W1/b1 column means -> centered rows into w1tab[h] =
//                   {W1c[0][h],W1c[1][h],W1c[2][h],W1c[3][h],W1c[4][h],b1c[h],0,0}
//               (b) w2pack A2-frags (32x32x16), 4 K-chunks:
//                   chunk c, lane l: row k_out=l&31 (<8 real), h=16c+8*(l>>5)+e
__global__ void prep_kernel(const float* __restrict__ rv,
                            const float* __restrict__ W1,
                            const float* __restrict__ b1,
                            const float* __restrict__ W2,
                            float* __restrict__ pt,
                            float* __restrict__ w1tab,
                            uint4* __restrict__ w2pack) {
    const int tid = threadIdx.x;
    const int bid = blockIdx.x;
    if (bid < 8) {
        const int idx = bid * 256 + tid;  // 0..2047
        const float x0 = rv[idx*4+0], y0 = rv[idx*4+1];
        const float vx = rv[idx*4+2] - x0, vy = rv[idx*4+3] - y0;
        const float rinv = rsqrtf(fmaf(vx, vx, vy * vy));
        float4 o; o.x = x0; o.y = y0; o.z = vx * rinv; o.w = vy * rinv;
        reinterpret_cast<float4*>(pt)[idx] = o;
    } else {
        __shared__ float mean[6];
        if (tid < 5)       { float m = 0.f; for (int h = 0; h < NH; ++h) m += W1[tid*NH+h]; mean[tid] = m * (1.f/NH); }
        else if (tid == 5) { float m = 0.f; for (int h = 0; h < NH; ++h) m += b1[h];        mean[5]   = m * (1.f/NH); }
        __syncthreads();
        if (tid < NH) {
            const int h = tid;
            w1tab[h*8+0] = W1[0*NH+h]-mean[0];
            w1tab[h*8+1] = W1[1*NH+h]-mean[1];
            w1tab[h*8+2] = W1[2*NH+h]-mean[2];
            w1tab[h*8+3] = W1[3*NH+h]-mean[3];
            w1tab[h*8+4] = W1[4*NH+h]-mean[4];
            w1tab[h*8+5] = b1[h]-mean[5];
            w1tab[h*8+6] = 0.f;
            w1tab[h*8+7] = 0.f;
        }
        // w2pack: 4 chunks x 64 lanes
        const int c = tid >> 6, l = tid & 63;
        const int row = l & 31;
        const int hb = 16*c + 8*(l >> 5);
        uint32_t dw[4];
        for (int t = 0; t < 4; ++t) {
            const int h0 = hb + 2*t;
            const float a = (row < 8) ? W2[h0*NK + row]     : 0.f;
            const float d = (row < 8) ? W2[(h0+1)*NK + row] : 0.f;
            dw[t] = pk_rne(a, d);
        }
        uint4 v; v.x = dw[0]; v.y = dw[1]; v.z = dw[2]; v.w = dw[3];
        w2pack[c*64 + l] = v;
    }
}

// sumsq of one 32x32 C pair (mu==0 exact by pre-centering)
#define SUMSQ(cA, cB, sqv) { \
    f32x2 q0 = cA.d[0]*cA.d[0], q1 = cA.d[1]*cA.d[1], q2 = cA.d[2]*cA.d[2], q3 = cA.d[3]*cA.d[3]; \
    q0 = __builtin_elementwise_fma(cA.d[4], cA.d[4], q0); \
    q1 = __builtin_elementwise_fma(cA.d[5], cA.d[5], q1); \
    q2 = __builtin_elementwise_fma(cA.d[6], cA.d[6], q2); \
    q3 = __builtin_elementwise_fma(cA.d[7], cA.d[7], q3); \
    q0 = __builtin_elementwise_fma(cB.d[0], cB.d[0], q0); \
    q1 = __builtin_elementwise_fma(cB.d[1], cB.d[1], q1); \
    q2 = __builtin_elementwise_fma(cB.d[2], cB.d[2], q2); \
    q3 = __builtin_elementwise_fma(cB.d[3], cB.d[3], q3); \
    q0 = __builtin_elementwise_fma(cB.d[4], cB.d[4], q0); \
    q1 = __builtin_elementwise_fma(cB.d[5], cB.d[5], q1); \
    q2 = __builtin_elementwise_fma(cB.d[6], cB.d[6], q2); \
    q3 = __builtin_elementwise_fma(cB.d[7], cB.d[7], q3); \
    q0 += q1; q2 += q3; q0 += q2; \
    sqv = q0[0] + q0[1]; }

// ---------------- main ----------------
// Per wave: 32 j, ITILE i. NO qpack stream: A1-fragments are computed
// in-register per i from lane-fixed centered-W1 rows (loaded once) and
// wave-uniform per-i point data. GEMM1: 2x mfma_32x32x16. LN: mu==0 exact;
// inv = rsqrt(E[x^2]+eps); cross-half reduce via permlane32_swap (no DS).
// Y C->B layout via permlane32_swap; GEMM2: 4 chained mfma_32x32x16 with
// b2 folded into acc init. 4 full-wave coalesced stores per i.
__global__ __launch_bounds__(256, 3) void rpe_kernel(
    const float* __restrict__ pt,
    const float* __restrict__ w1tab,
    const uint4* __restrict__ w2pack,
    const float* __restrict__ gamma,
    const float* __restrict__ beta,
    const float* __restrict__ b2,
    float* __restrict__ out) {
    const int tid  = threadIdx.x;
    const int wave = tid >> 6;
    const int lane = tid & 63;
    const int jj   = lane & 31;
    const int hi   = lane >> 5;
    const int b  = blockIdx.z;
    const int j0 = blockIdx.x * 128 + wave * 32;
    const int iBase = blockIdx.y * ITILE;

    const uint32_t hm = hi ? 0u : 0xFFFFFFFFu;

    const float4 pj = reinterpret_cast<const float4*>(pt)[b*NN + j0 + jj];
    const float xj = pj.x, yj = pj.y;
    const uint32_t d0 = pk_rne(pj.z, pj.w) & hm;
    const uint32_t d1 = pk_rne(xj, yj) & hm;

    // lane-fixed centered W1 rows: tile0 -> h=lane, tile1 -> h=lane+32 (lanes<32)
    float4 wA0 = {0,0,0,0}, wA1 = {0,0,0,0}, wB0 = {0,0,0,0}, wB1 = {0,0,0,0};
    if (lane < 32) {
        const float4* t4 = reinterpret_cast<const float4*>(w1tab);
        wA0 = t4[lane*2];        wA1 = t4[lane*2+1];        // (w0,w1,w2,w3) (w4,bbc,_,_)
        wB0 = t4[(lane+32)*2];   wB1 = t4[(lane+32)*2+1];
    }
    const uint32_t w0fA = pk_rne(wA0.x, 0.f);  // low half = w0 as f16
    const uint32_t w0fB = pk_rne(wB0.x, 0.f);

    // gamma/beta fp16 pairs: word (T,m) -> rows h0,h0+1 ; h0 = 32T+8(m>>1)+2(m&1)+4hi
    uint32_t gph[16], bph[16];
#pragma unroll
    for (int T = 0; T < 2; ++T)
#pragma unroll
        for (int m = 0; m < 8; ++m) {
            const int h0 = 32*T + 8*(m>>1) + 2*(m&1) + 4*hi;
            gph[T*8+m] = pk_rne(gamma[h0], gamma[h0+1]);
            bph[T*8+m] = pk_rne(beta[h0],  beta[h0+1]);
        }

    FragU a2[4];
#pragma unroll
    for (int c = 0; c < 4; ++c) a2[c].q = w2pack[c*64 + lane];
    float b2v[4];
#pragma unroll
    for (int r = 0; r < 4; ++r) b2v[r] = b2[4*hi + r];

    const float4* ptb = reinterpret_cast<const float4*>(pt) + b*NN + iBase;
    float4 piv = ptb[0];

    const f32x16 z16 = {0,0,0,0,0,0,0,0,0,0,0,0,0,0,0,0};
    half2t z2; z2[0] = (_Float16)0.f; z2[1] = (_Float16)0.f;
    const size_t plane = (size_t)NN * NN;
    float* op = out + (size_t)(b*NK + 4*hi)*plane + (size_t)iBase*NN + (j0 + jj);

    for (int ii = 0; ii < ITILE; ++ii) {
        const float x0 = piv.x, y0 = piv.y, ci = piv.z, si = piv.w;
        if (ii + 1 < ITILE) piv = ptb[ii + 1];

        // wave-uniform helpers
        const float u1 = fmaf(x0, ci, y0 * si);
        const float u2 = fmaf(y0, ci, -x0 * si);

        // A1-fragments in-register (tile0 from wA, tile1 from wB)
        FragU qf0, qf1;
        {
            const float qc = fmaf(wA0.y, ci,  wA0.z * si);
            const float qs = fmaf(wA0.y, si, -wA0.z * ci);
            const float qx = fmaf(-wA0.w, ci,  wA1.x * si);
            const float qy = fmaf(-wA0.w, si, -wA1.x * ci);
            const float cn = fmaf(wA0.w, u1, fmaf(wA1.x, u2, wA1.y));
            qf0.u[0] = pk_rne(qc, qs); qf0.u[1] = pk_rne(qx, qy);
            H2U c16; c16.p = __builtin_amdgcn_cvt_pkrtz(0.f, cn);
            qf0.u[2] = w0fA | (c16.u & 0xFFFF0000u); qf0.u[3] = 0u;
        }
        {
            const float qc = fmaf(wB0.y, ci,  wB0.z * si);
            const float qs = fmaf(wB0.y, si, -wB0.z * ci);
            const float qx = fmaf(-wB0.w, ci,  wB1.x * si);
            const float qy = fmaf(-wB0.w, si, -wB1.x * ci);
            const float cn = fmaf(wB0.w, u1, fmaf(wB1.x, u2, wB1.y));
            qf1.u[0] = pk_rne(qc, qs); qf1.u[1] = pk_rne(qx, qy);
            H2U c16; c16.p = __builtin_amdgcn_cvt_pkrtz(0.f, cn);
            qf1.u[2] = w0fB | (c16.u & 0xFFFF0000u); qf1.u[3] = 0u;
        }

        // per-pair feature (log-dist)
        const float dx = x0 - xj, dy = y0 - yj;
        const float g0v = logf(sqrtf(fmaf(dx, dx, dy * dy)) + 1e-5f);
        H2U e0; e0.p = __builtin_amdgcn_cvt_pkrtz(g0v, 1.0f);
        FragU bf; bf.u[0] = d0; bf.u[1] = d1; bf.u[2] = e0.u & hm; bf.u[3] = 0u;

        C32U cA, cB;
        cA.v = __builtin_amdgcn_mfma_f32_32x32x16_f16(qf0.h, bf.h, z16, 0, 0, 0);
        cB.v = __builtin_amdgcn_mfma_f32_32x32x16_f16(qf1.h, bf.h, z16, 0, 0, 0);

        float sq;
        SUMSQ(cA, cB, sq)
        sq = wave_sum_half(sq);
        const float inv = rsqrtf(fmaf(sq, 1.f/64.f, 1e-5f));
        H2U inv2u; inv2u.p = __builtin_amdgcn_cvt_pkrtz(inv, inv);
        const half2t inv2 = inv2u.h;

        // normalize + affine + relu (packed f16)
        uint32_t yw[16];
#pragma unroll
        for (int m = 0; m < 8; ++m) {
            H2U x; x.p = __builtin_amdgcn_cvt_pkrtz(cA.d[m][0], cA.d[m][1]);
            half2t xh = x.h * inv2;
            H2U gg, bb; gg.u = gph[m]; bb.u = bph[m];
            half2t y = __builtin_elementwise_fma(xh, gg.h, bb.h);
            y = __builtin_elementwise_max(y, z2);
            H2U o; o.h = y; yw[m] = o.u;
        }
#pragma unroll
        for (int m = 0; m < 8; ++m) {
            H2U x; x.p = __builtin_amdgcn_cvt_pkrtz(cB.d[m][0], cB.d[m][1]);
            half2t xh = x.h * inv2;
            H2U gg, bb; gg.u = gph[8+m]; bb.u = bph[8+m];
            half2t y = __builtin_elementwise_fma(xh, gg.h, bb.h);
            y = __builtin_elementwise_max(y, z2);
            H2U o; o.h = y; yw[8+m] = o.u;
        }

        // GEMM2: B-frags via lane-half swaps, 4 chained MFMAs, b2 in acc init
        C32U c2; c2.v = z16;
        c2.f[0] = b2v[0]; c2.f[1] = b2v[1]; c2.f[2] = b2v[2]; c2.f[3] = b2v[3];
#pragma unroll
        for (int c = 0; c < 4; ++c) {
            uint32_t w0, w1, w2, w3;
            half_swap(yw[4*c + 0], yw[4*c + 2], w0, w2);
            half_swap(yw[4*c + 1], yw[4*c + 3], w1, w3);
            FragU Bf; Bf.u[0] = w0; Bf.u[1] = w1; Bf.u[2] = w2; Bf.u[3] = w3;
            c2.v = __builtin_amdgcn_mfma_f32_32x32x16_f16(a2[c].h, Bf.h, c2.v, 0, 0, 0);
        }

        op[0]       = c2.f[0];
        op[plane]   = c2.f[1];
        op[2*plane] = c2.f[2];
        op[3*plane] = c2.f[3];
        op += NN;
    }
}

extern "C" void kernel_launch(void* const* d_in, const int* in_sizes, int n_in,
                              void* d_out, int out_size, void* d_ws, size_t ws_size,
                              hipStream_t stream) {
    const float* rv    = (const float*)d_in[0];
    const float* W1    = (const float*)d_in[1];
    const float* b1    = (const float*)d_in[2];
    const float* gamma = (const float*)d_in[3];
    const float* beta  = (const float*)d_in[4];
    const float* W2    = (const float*)d_in[5];
    const float* b2    = (const float*)d_in[6];
    float* out = (float*)d_out;

    float* ws = (float*)d_ws;
    float* pt     = ws;                       // 2048*4 f32 = 32 KB
    float* w1tab  = ws + 8192;                // 64*8 f32 = 2 KB
    uint4* w2pack = (uint4*)(ws + 8192 + 512);// 4 KB

    prep_kernel<<<9, 256, 0, stream>>>(rv, W1, b1, W2, pt, w1tab, w2pack);

    dim3 grid(NN / 128, NN / ITILE, NB);
    rpe_kernel<<<grid, 256, 0, stream>>>(pt, w1tab, w2pack, gamma, beta, b2, out);
}